// Round 7
// baseline (364.618 us; speedup 1.0000x reference)
//
#include <hip/hip_runtime.h>
#include <hip/hip_bf16.h>

#define LO 506      // L_out
#define LL 512      // L
#define CC 128      // C
#define FF 128      // F
#define KC 896      // K*C (reduction dim)
#define BK 32       // K-tile
#define NK 28       // 896/32
#define NB 1012     // grid: 2 blocks (batch halves) per l
#define XS 40       // Xs row stride bf16 (32+8 pad, 80 B rows: 16B-aligned, bank-spread)
#define WS 40       // Wt row stride bf16

typedef __attribute__((ext_vector_type(8))) short short8;     // 8 bf16 = 4 VGPR
typedef __attribute__((ext_vector_type(4))) float floatx4;
typedef __attribute__((ext_vector_type(4))) unsigned int uintx4;
typedef __attribute__((ext_vector_type(2))) unsigned int uintx2;
typedef unsigned short ushort_t;

// Native RNE f32->bf16 (backend fuses pairs into v_cvt_pk_bf16_f32)
static __device__ __forceinline__ unsigned int pk2(float a, float b) {
    __hip_bfloat16 ha = __float2bfloat16(a);
    __hip_bfloat16 hb = __float2bfloat16(b);
    unsigned short ua, ub;
    __builtin_memcpy(&ua, &ha, 2);
    __builtin_memcpy(&ub, &hb, 2);
    return (unsigned int)ua | ((unsigned int)ub << 16);
}

// 1012 blocks: (l, batch-half) pairs, chunk-swizzled so each XCD's co-resident
// blocks cover ~32 CONTIGUOUS l-values -> per-XCD x window ~2.5 MB < 4 MB L2
// (x re-reads become L2 hits instead of L3/HBM fabric traffic). Sibling blocks
// (same l) land on the same XCD -> W[l] HBM-fetched once, second reader hits
// L2 -> W loads are PLAIN (not nt; nt would defeat the share). Out stores nt.
// 512 thr = 8 waves (2 batch-32 x 4 f-32 wave grid), 64b x 128f per block.
// ~70 live VGPR << 128 cap; LDS 30 KB; 2 blocks/CU.
__global__ __launch_bounds__(512, 4)
void local_block_kernel(const float* __restrict__ x,
                        const float* __restrict__ wg,
                        const float* __restrict__ bias,
                        const float* __restrict__ gamma,
                        const float* __restrict__ beta,
                        const float* __restrict__ mmean,
                        const float* __restrict__ mvar,
                        float* __restrict__ out)
{
    // ---- bijective XCD-chunk swizzle (nwg=1012: chunks 127x4, 126x4)
    const int bid = blockIdx.x;
    const int xcd = bid & 7;
    const int idx = bid >> 3;
    const int q8  = NB >> 3;              // 126
    const int r8  = NB & 7;               // 4
    const int lin = (xcd < r8) ? xcd * (q8 + 1) + idx
                               : r8 * (q8 + 1) + (xcd - r8) * q8 + idx;
    const int l     = lin >> 1;           // output position
    const int bhalf = lin & 1;            // batch 64-half

    const int t    = threadIdx.x;         // 512 threads = 8 waves
    const int lane = t & 63;
    const int wave = t >> 6;              // 0..7
    const int q    = lane >> 4;           // k-group within wave
    const int l16  = lane & 15;
    const int wrow = wave >> 2;           // batch 32-block (0..1)
    const int wcol = wave & 3;            // f 32-block (0..3)

    __shared__ __align__(16) ushort_t Xs[2][64 * XS];    // 2 x 5 KB
    __shared__ __align__(16) ushort_t Wt[2][128 * WS];   // 2 x 10 KB (30 KB total)

    // ---- A staging: thread -> (row = t>>3 in 0..63, k-chunk = (t&7)*4); 4 floats
    const int am  = t >> 3;
    const int ak0 = (t & 7) * 4;
    const float* aptr = x + (size_t)(bhalf * 64 + am) * (LL * CC) + l * CC + ak0;

    // ---- W staging: thread -> (f = t&127, k 8-group = (t>>7)*8); 8 strided dwords
    const int wf  = t & 127;
    const int wk  = (t >> 7) * 8;         // 0,8,16,24
    const float* wptr = wg + (size_t)l * (KC * FF) + wf;

    floatx4 acc[2][2] = {};               // 16 fp32 accumulators (2 mi x 2 ni)

    floatx4 areg0, areg1;                 // alternating A prefetch (2-tile slack)
    float   wreg0[8], wreg1[8];           // alternating W prefetch (2-tile slack)

#define LOAD_A(AR, KT) { AR = *(const floatx4*)(aptr + (KT) * BK); }

#define LOAD_W(WR, KT) { const float* p = wptr + (size_t)((KT) * BK + wk) * FF; \
        _Pragma("unroll") for (int j = 0; j < 8; ++j)                           \
            WR[j] = p[j * FF]; }   /* plain load: L2-cached, shared w/ sibling */

#define STAGE(S, AR, WR) {                                                      \
        uintx2 av = { pk2(AR.x, AR.y), pk2(AR.z, AR.w) };                       \
        *(uintx2*)&Xs[S][am * XS + ak0] = av;                                   \
        uintx4 wv = { pk2(WR[0], WR[1]), pk2(WR[2], WR[3]),                     \
                      pk2(WR[4], WR[5]), pk2(WR[6], WR[7]) };                   \
        *(uintx4*)&Wt[S][wf * WS + wk] = wv; }

    // LDS-only drain barrier: prefetch global loads stay in flight (no vmcnt)
#define BAR() {                                                                 \
        asm volatile("s_waitcnt lgkmcnt(0)" ::: "memory");                      \
        __builtin_amdgcn_s_barrier();                                           \
        asm volatile("" ::: "memory"); }

#define COMPUTE(S) {                                                            \
        short8 af[2], bfr[2];                                                   \
        _Pragma("unroll") for (int mi = 0; mi < 2; ++mi)                        \
            af[mi] = *(const short8*)&Xs[S][(wrow*32 + mi*16 + l16) * XS + q*8];\
        _Pragma("unroll") for (int ni = 0; ni < 2; ++ni)                        \
            bfr[ni] = *(const short8*)&Wt[S][(wcol*32 + ni*16 + l16) * WS + q*8];\
        _Pragma("unroll") for (int mi = 0; mi < 2; ++mi)                        \
            _Pragma("unroll") for (int ni = 0; ni < 2; ++ni)                    \
                acc[mi][ni] = __builtin_amdgcn_mfma_f32_16x16x32_bf16(          \
                    af[mi], bfr[ni], acc[mi][ni], 0, 0, 0); }

    LOAD_A(areg0, 0); LOAD_W(wreg0, 0);
    LOAD_A(areg1, 1); LOAD_W(wreg1, 1);

    for (int kt = 0; kt < NK; kt += 2) {
        // ---- tile kt -> LDS buffer 0
        STAGE(0, areg0, wreg0);
        if (kt + 2 < NK) { LOAD_A(areg0, kt + 2); LOAD_W(wreg0, kt + 2); }
        BAR();
        COMPUTE(0);
        // ---- tile kt+1 -> LDS buffer 1
        STAGE(1, areg1, wreg1);
        if (kt + 3 < NK) { LOAD_A(areg1, kt + 3); LOAD_W(wreg1, kt + 3); }
        BAR();
        COMPUTE(1);
    }

    // ---- epilogue: fold bias + BN into per-f scale/offset, relu, nt store
#pragma unroll
    for (int ni = 0; ni < 2; ++ni) {
        int f = wcol*32 + ni*16 + l16;
        float inv = gamma[f] * rsqrtf(mvar[f] + 1e-3f);
        float off = bias[l * FF + f] * inv + beta[f] - mmean[f] * inv;
#pragma unroll
        for (int mi = 0; mi < 2; ++mi) {
#pragma unroll
            for (int rg = 0; rg < 4; ++rg) {
                int b = bhalf*64 + wrow*32 + mi*16 + q*4 + rg;  // C/D: row=(lane>>4)*4+reg
                float v = acc[mi][ni][rg] * inv + off;
                __builtin_nontemporal_store(fmaxf(v, 0.0f),
                    &out[((size_t)b * LO + l) * FF + f]);
            }
        }
    }
#undef LOAD_A
#undef LOAD_W
#undef STAGE
#undef BAR
#undef COMPUTE
}

extern "C" void kernel_launch(void* const* d_in, const int* in_sizes, int n_in,
                              void* d_out, int out_size, void* d_ws, size_t ws_size,
                              hipStream_t stream) {
    const float* x     = (const float*)d_in[0];
    const float* w     = (const float*)d_in[1];
    const float* bias  = (const float*)d_in[2];
    const float* gamma = (const float*)d_in[3];
    const float* beta  = (const float*)d_in[4];
    const float* mmean = (const float*)d_in[5];
    const float* mvar  = (const float*)d_in[6];
    float* out = (float*)d_out;

    local_block_kernel<<<dim3(NB), dim3(512), 0, stream>>>(
        x, w, bias, gamma, beta, mmean, mvar, out);
}

// Round 8
// 346.233 us; speedup vs baseline: 1.0531x; 1.0531x over previous
//
#include <hip/hip_runtime.h>
#include <hip/hip_bf16.h>

#define LO 506      // L_out
#define LL 512      // L
#define CC 128      // C
#define FF 128      // F
#define KC 896      // K*C (reduction dim)
#define BK 32       // K-tile
#define NK 28       // 896/32
#define XS 40       // Xs row stride in bf16 (32 + 8 pad; 80 B rows: 16B-aligned b128, 2-way banks = free)
#define WS 40       // Wt row stride in bf16

typedef __attribute__((ext_vector_type(8))) short short8;     // 8 bf16 = 4 VGPR (MFMA operand)
typedef __attribute__((ext_vector_type(4))) float floatx4;    // MFMA acc / float4 load
typedef __attribute__((ext_vector_type(4))) unsigned int uintx4;
typedef unsigned short ushort_t;

// Native RNE f32->bf16 (backend fuses pairs into v_cvt_pk_bf16_f32)
static __device__ __forceinline__ unsigned int pk2(float a, float b) {
    __hip_bfloat16 ha = __float2bfloat16(a);
    __hip_bfloat16 hb = __float2bfloat16(b);
    unsigned short ua, ub;
    __builtin_memcpy(&ua, &ha, 2);
    __builtin_memcpy(&ub, &hb, 2);
    return (unsigned int)ua | ((unsigned int)ub << 16);
}

// grid = 506, one block per l, 512 threads = 8 waves, full 128b x 128f tile.
// Base = R3/R5 champion (347 us). NEW: K-loop PHASE ROTATION. Block l
// processes k-tiles in order (s, s+1, .., 27, 0, .., s-1) with
// s = (-4l) mod 28. Then block l touches x-row r at wall-phase 4r mod 28:
// the 7 blocks sharing row r (l = r-6..r, same XCD chunk) touch it
// SIMULTANEOUSLY -> 1 HBM fetch + 6 L2/MSHR hits, instead of touches
// spread ~9.6 us apart while the nt W stream turns L2 over every ~4.5 us.
// Accumulation over k is order-independent; each A/W tile loaded once.
__global__ __launch_bounds__(512, 4)
void local_block_kernel(const float* __restrict__ x,
                        const float* __restrict__ wg,
                        const float* __restrict__ bias,
                        const float* __restrict__ gamma,
                        const float* __restrict__ beta,
                        const float* __restrict__ mmean,
                        const float* __restrict__ mvar,
                        float* __restrict__ out)
{
    // ---- bijective XCD-chunk swizzle (nwg=506, 8 XCDs: chunks 64,64,63x6)
    const int bid = blockIdx.x;
    const int xcd = bid & 7;
    const int idx = bid >> 3;
    const int q8  = LO >> 3;              // 63
    const int r8  = LO & 7;               // 2
    const int l   = (xcd < r8) ? xcd * (q8 + 1) + idx
                               : r8 * (q8 + 1) + (xcd - r8) * q8 + idx;

    const int t    = threadIdx.x;         // 512 threads = 8 waves
    const int lane = t & 63;
    const int wave = t >> 6;              // 0..7
    const int q    = lane >> 4;           // quad within wave (k-group)
    const int l16  = lane & 15;
    const int wr   = wave >> 1;           // wave row: batch 32-block (0..3)
    const int wc   = wave & 1;            // wave col: f 64-half

    __shared__ __align__(16) ushort_t Xs[2][128 * XS];   // 2 x 10 KB
    __shared__ __align__(16) ushort_t Wt[2][128 * WS];   // 2 x 10 KB  (40 KB total)

    // ---- A staging map: thread -> (row = t>>2, k-chunk = (t&3)*8); 8 floats = 2 float4
    const int am  = t >> 2;
    const int ak0 = (t & 3) * 8;
    const float* aptr = x + (size_t)am * (LL * CC) + l * CC + ak0;

    // ---- W staging map: thread -> (f = t&127, k 8-group = (t>>7)*8); 8 strided dword loads
    const int wf  = t & 127;
    const int wk  = (t >> 7) * 8;         // 0,8,16,24
    const float* wptr = wg + (size_t)l * (KC * FF) + wf;

    floatx4 acc[2][4] = {};               // 32 fp32 accumulators

    floatx4 areg0[2], areg1[2];           // 2-deep A prefetch (16 VGPR)
    float   wreg0[8], wreg1[8];           // 2-deep W prefetch (16 VGPR)

#define LOAD_A(AR, KP) { const float* p = aptr + (KP) * BK;                     \
        AR[0] = *(const floatx4*)(p);                                           \
        AR[1] = *(const floatx4*)(p + 4); }

#define LOAD_W(WR, KP) { const float* p = wptr + (size_t)((KP) * BK + wk) * FF; \
        _Pragma("unroll") for (int j = 0; j < 8; ++j)                           \
            WR[j] = __builtin_nontemporal_load(p + j * FF); }

#define STAGE(S, AR, WR) {                                                      \
        uintx4 av = { pk2(AR[0].x, AR[0].y), pk2(AR[0].z, AR[0].w),             \
                      pk2(AR[1].x, AR[1].y), pk2(AR[1].z, AR[1].w) };           \
        *(uintx4*)&Xs[S][am * XS + ak0] = av;                                   \
        uintx4 wv = { pk2(WR[0], WR[1]), pk2(WR[2], WR[3]),                     \
                      pk2(WR[4], WR[5]), pk2(WR[6], WR[7]) };                   \
        *(uintx4*)&Wt[S][wf * WS + wk] = wv; }

    // LDS-only drain barrier: prefetch global loads stay in flight (no vmcnt)
#define BAR() {                                                                 \
        asm volatile("s_waitcnt lgkmcnt(0)" ::: "memory");                      \
        __builtin_amdgcn_s_barrier();                                           \
        asm volatile("" ::: "memory"); }

#define COMPUTE(S) {                                                            \
        short8 af[2], bfr[4];                                                   \
        _Pragma("unroll") for (int mi = 0; mi < 2; ++mi)                        \
            af[mi] = *(const short8*)&Xs[S][(wr*32 + mi*16 + l16) * XS + q*8];  \
        _Pragma("unroll") for (int ni = 0; ni < 4; ++ni)                        \
            bfr[ni] = *(const short8*)&Wt[S][(wc*64 + ni*16 + l16) * WS + q*8]; \
        _Pragma("unroll") for (int mi = 0; mi < 2; ++mi)                        \
            _Pragma("unroll") for (int ni = 0; ni < 4; ++ni)                    \
                acc[mi][ni] = __builtin_amdgcn_mfma_f32_16x16x32_bf16(          \
                    af[mi], bfr[ni], acc[mi][ni], 0, 0, 0); }

#define WRAP(K) { if ((K) >= NK) (K) -= NK; }

    // ---- phase-rotated start: s0 = (-4*l) mod 28
    const int s0 = (NK - 4 * (l % 7)) % NK;
    int kp0 = s0;                         // phys tile for even logical slot
    int kp1 = s0 + 1; WRAP(kp1);          // phys tile for odd logical slot
    int kpa = kp1 + 1; WRAP(kpa);         // phys tile of next prefetch target

    LOAD_A(areg0, kp0); LOAD_W(wreg0, kp0);
    LOAD_A(areg1, kp1); LOAD_W(wreg1, kp1);

    for (int kt = 0; kt < NK; kt += 2) {
        // ---- logical tile kt (phys via rotation) -> LDS buffer 0
        STAGE(0, areg0, wreg0);
        if (kt + 2 < NK) { LOAD_A(areg0, kpa); LOAD_W(wreg0, kpa); }
        kpa += 1; WRAP(kpa);
        BAR();
        COMPUTE(0);
        // ---- logical tile kt+1 -> LDS buffer 1
        STAGE(1, areg1, wreg1);
        if (kt + 3 < NK) { LOAD_A(areg1, kpa); LOAD_W(wreg1, kpa); }
        kpa += 1; WRAP(kpa);
        BAR();
        COMPUTE(1);
    }

    // ---- epilogue: fold bias + BN into per-f scale/offset, relu, nontemporal store
#pragma unroll
    for (int ni = 0; ni < 4; ++ni) {
        int f = wc*64 + ni*16 + l16;
        float inv = gamma[f] * rsqrtf(mvar[f] + 1e-3f);
        float off = bias[l * FF + f] * inv + beta[f] - mmean[f] * inv;
#pragma unroll
        for (int mi = 0; mi < 2; ++mi) {
#pragma unroll
            for (int rg = 0; rg < 4; ++rg) {
                int b = wr*32 + mi*16 + q*4 + rg;   // C/D: row=(lane>>4)*4+reg
                float v = acc[mi][ni][rg] * inv + off;
                __builtin_nontemporal_store(fmaxf(v, 0.0f),
                    &out[((size_t)b * LO + l) * FF + f]);
            }
        }
    }
#undef LOAD_A
#undef LOAD_W
#undef STAGE
#undef BAR
#undef COMPUTE
#undef WRAP
}

extern "C" void kernel_launch(void* const* d_in, const int* in_sizes, int n_in,
                              void* d_out, int out_size, void* d_ws, size_t ws_size,
                              hipStream_t stream) {
    const float* x     = (const float*)d_in[0];
    const float* w     = (const float*)d_in[1];
    const float* bias  = (const float*)d_in[2];
    const float* gamma = (const float*)d_in[3];
    const float* beta  = (const float*)d_in[4];
    const float* mmean = (const float*)d_in[5];
    const float* mvar  = (const float*)d_in[6];
    float* out = (float*)d_out;

    local_block_kernel<<<dim3(LO), dim3(512), 0, stream>>>(
        x, w, bias, gamma, beta, mmean, mvar, out);
}